// Round 3
// baseline (170.112 us; speedup 1.0000x reference)
//
#include <hip/hip_runtime.h>
#include <hip/hip_bf16.h>

#define SDIM 2048
#define BATCH 4
#define DMODEL 512
#define NH 8
#define NKV 2
#define HD 64

typedef __bf16 bf16x8 __attribute__((ext_vector_type(8)));
typedef float floatx16 __attribute__((ext_vector_type(16)));
typedef unsigned short u16;
typedef unsigned int u32;

#define MFMA32 __builtin_amdgcn_mfma_f32_32x32x16_bf16
#define ZERO16 {0.f,0.f,0.f,0.f,0.f,0.f,0.f,0.f,0.f,0.f,0.f,0.f,0.f,0.f,0.f,0.f}
// softmax scale with log2(e) folded: exp(s*0.125) = exp2(s*0.125*log2e)
#define QSCALE 0.18033688011112042f

__device__ __forceinline__ u16 f2bf(float f) {
  union { float f; u32 u; } a; a.f = f;
  u32 r = a.u + 0x7fffu + ((a.u >> 16) & 1u);
  return (u16)(r >> 16);
}
// pack two f32 -> (lo, hi) bf16 pair via v_cvt_pk_bf16_f32
__device__ __forceinline__ u32 pkbf(float lo, float hi) {
  __hip_bfloat162 h = __float22bfloat162_rn(float2{lo, hi});
  union { __hip_bfloat162 h; u32 u; } c; c.h = h;
  return c.u;
}
__device__ __forceinline__ float bflo(u32 u) {
  union { u32 u; float f; } c; c.u = u << 16; return c.f;
}
__device__ __forceinline__ float bfhi(u32 u) {
  union { u32 u; float f; } c; c.u = u & 0xffff0000u; return c.f;
}
// 8 f32 (two float4) -> bf16x8
__device__ __forceinline__ bf16x8 cvt8(float4 a, float4 b) {
  union { u32 u[4]; bf16x8 v; } c;
  c.u[0] = pkbf(a.x, a.y); c.u[1] = pkbf(a.z, a.w);
  c.u[2] = pkbf(b.x, b.y); c.u[3] = pkbf(b.z, b.w);
  return c.v;
}
// combine two packed-bf16-pair partials with normalization -> bf16x8
__device__ __forceinline__ bf16x8 comb8(uint4 a, uint4 b, float inv) {
  union { u32 u[4]; bf16x8 v; } c;
  c.u[0] = pkbf((bflo(a.x) + bflo(b.x)) * inv, (bfhi(a.x) + bfhi(b.x)) * inv);
  c.u[1] = pkbf((bflo(a.y) + bflo(b.y)) * inv, (bfhi(a.y) + bfhi(b.y)) * inv);
  c.u[2] = pkbf((bflo(a.z) + bflo(b.z)) * inv, (bfhi(a.z) + bfhi(b.z)) * inv);
  c.u[3] = pkbf((bflo(a.w) + bflo(b.w)) * inv, (bfhi(a.w) + bfhi(b.w)) * inv);
  return c.v;
}

// ---- weights -> WT[1280][512] bf16 transposed (x conversion fused into gemm_qkv) ----
__global__ __launch_bounds__(256) void cvt_kernel(const float* __restrict__ Wq,
                                                  const float* __restrict__ Wk,
                                                  const float* __restrict__ Wv,
                                                  const float* __restrict__ Wo,
                                                  u16* __restrict__ WT) {
  int i = blockIdx.x * 256 + threadIdx.x;  // < 1280*512
  int n = i >> 9, k = i & 511;
  float v;
  if (n < 512)       v = Wq[k * 512 + n];
  else if (n < 640)  v = Wk[k * 128 + (n - 512)];
  else if (n < 768)  v = Wv[k * 128 + (n - 640)];
  else               v = Wo[k * 512 + (n - 768)];
  WT[i] = f2bf(v);
}

// ---- fused QKV projection: 64x64 tile, BK=32, distance-2 register prefetch,
// LDS dbuf stride-40, 32x32 MFMA, 4 waves (2m x 2n). A read directly from x
// (fp32) with inline bf16 conversion at the LDS-write point. Q scaled by
// QSCALE; Q/K head-major [B,nh,S,64]; V written TRANSPOSED [B,NKV,64,S].
__global__ __launch_bounds__(256, 4) void gemm_qkv_kernel(const float* __restrict__ x,
                                                          const u16* __restrict__ WT,
                                                          const float* __restrict__ bq,
                                                          const float* __restrict__ bk,
                                                          const float* __restrict__ bv,
                                                          u16* __restrict__ Qb,
                                                          u16* __restrict__ Kb,
                                                          u16* __restrict__ Vt) {
  __shared__ __align__(16) u16 abuf[2][64 * 40];
  __shared__ __align__(16) u16 bbuf[2][64 * 40];
  int tid = threadIdx.x;
  int lane = tid & 63, wave = tid >> 6;
  int l31 = lane & 31, half = lane >> 5;
  int m0 = blockIdx.y * 64;
  int n0 = blockIdx.x * 64;
  int row = tid >> 2, ch = tid & 3;
  const float* Asrc = x + (size_t)(m0 + row) * DMODEL + ch * 8;
  const u16* Bsrc = WT + (size_t)(n0 + row) * DMODEL + ch * 8;
  int wo = row * 40 + ch * 8;

  float4 rxa[2][2];
  bf16x8 rB[2];
  rxa[0][0] = *(const float4*)Asrc;
  rxa[0][1] = *(const float4*)(Asrc + 4);
  rB[0] = *(const bf16x8*)Bsrc;
  rxa[1][0] = *(const float4*)(Asrc + 32);
  rxa[1][1] = *(const float4*)(Asrc + 36);
  rB[1] = *(const bf16x8*)(Bsrc + 32);
  *(bf16x8*)(abuf[0] + wo) = cvt8(rxa[0][0], rxa[0][1]);
  *(bf16x8*)(bbuf[0] + wo) = rB[0];
  __syncthreads();

  floatx16 acc = ZERO16;
  int mw = (wave & 1) * 32, nw = (wave >> 1) * 32;
  for (int it = 0; it < 16; ++it) {
    if (it < 14) {
      rxa[it & 1][0] = *(const float4*)(Asrc + (it + 2) * 32);
      rxa[it & 1][1] = *(const float4*)(Asrc + (it + 2) * 32 + 4);
      rB[it & 1] = *(const bf16x8*)(Bsrc + (it + 2) * 32);
    }
    const u16* ab = abuf[it & 1];
    const u16* bb = bbuf[it & 1];
#pragma unroll
    for (int ks = 0; ks < 2; ++ks) {
      bf16x8 af = *(const bf16x8*)(ab + (mw + l31) * 40 + (2 * ks + half) * 8);
      bf16x8 bf = *(const bf16x8*)(bb + (nw + l31) * 40 + (2 * ks + half) * 8);
      acc = MFMA32(af, bf, acc, 0, 0, 0);
    }
    if (it < 15) {
      *(bf16x8*)(abuf[(it + 1) & 1] + wo) = cvt8(rxa[(it + 1) & 1][0], rxa[(it + 1) & 1][1]);
      *(bf16x8*)(bbuf[(it + 1) & 1] + wo) = rB[(it + 1) & 1];
    }
    __syncthreads();
  }

  int col = n0 + nw + l31;
  int b4 = m0 >> 11;  // batch fixed per block (m-tile within one batch)
  if (col >= 640) {
    // V: write transposed rows of Vt[b,kv,d,s] as ushort4 (4 consecutive s)
    int lc = col - 640;
    float bl = bv[lc];
    int hkv = lc >> 6, d = lc & 63;
    u16* vrow = Vt + ((size_t)(b4 * NKV + hkv) * HD + d) * SDIM;
#pragma unroll
    for (int g = 0; g < 4; ++g) {
      int s = (m0 + mw + 8 * g + 4 * half) & 2047;
      ushort4 t;
      t.x = f2bf(acc[4 * g + 0] + bl);
      t.y = f2bf(acc[4 * g + 1] + bl);
      t.z = f2bf(acc[4 * g + 2] + bl);
      t.w = f2bf(acc[4 * g + 3] + bl);
      *(ushort4*)(vrow + s) = t;
    }
  } else {
    u16* outp; const float* bias; float scale; int nhreg, lc;
    if (col < 512) { outp = Qb; bias = bq; scale = QSCALE; nhreg = NH;  lc = col; }
    else           { outp = Kb; bias = bk; scale = 1.0f;   nhreg = NKV; lc = col - 512; }
    float bl = bias[lc];
    int h = lc >> 6, d = lc & 63;
    u16* base = outp + ((size_t)(b4 * nhreg + h) * SDIM) * HD + d;
#pragma unroll
    for (int r = 0; r < 16; ++r) {
      int s = (m0 + mw + (r & 3) + 8 * (r >> 2) + 4 * half) & 2047;
      base[(size_t)s * HD] = f2bf((acc[r] + bl) * scale);
    }
  }
}

// ---- O projection with FUSED key-half combine: A-tile = (Op0+Op1)/(L0+L1)
// computed inline during LDS staging. Same 64x64 pipeline, fp32 output. ----
__global__ __launch_bounds__(256, 4) void gemm_out_kernel(const u32* __restrict__ Op,
                                                          const float* __restrict__ Lp,
                                                          const u16* __restrict__ WTo,
                                                          const float* __restrict__ bo,
                                                          float* __restrict__ out) {
  __shared__ __align__(16) u16 abuf[2][64 * 40];
  __shared__ __align__(16) u16 bbuf[2][64 * 40];
  int tid = threadIdx.x;
  int lane = tid & 63, wave = tid >> 6;
  int l31 = lane & 31, half = lane >> 5;
  int m0 = blockIdx.y * 64;
  int n0 = blockIdx.x * 64;
  int row = tid >> 2, ch = tid & 3;
  int m = m0 + row;
  int bb = m >> 11, ss = m & 2047;
  // A source: packed partials. For k-chunk (it, ch): h = it>>1,
  // u32 index j0 = (it&1)*16 + ch*4. rowA = (bb*8+h)*2048+ss (p=0),
  // rowB = rowA + 65536 (p=1). Op u32 off = row*32 + j0.
  const u32* OpA = Op + ((size_t)bb * 16384 + ss) * 32 + ch * 4;
  const float* LpA = Lp + (size_t)bb * 16384 + ss;
  const u16* Bsrc = WTo + (size_t)(n0 + row) * DMODEL + ch * 8;
  int wo = row * 40 + ch * 8;

  uint4 ua[2], ub[2];
  float la[2], lb[2];
  bf16x8 rB[2];
#pragma unroll
  for (int j = 0; j < 2; ++j) {
    size_t od = (size_t)(j >> 1) * 65536 + (j & 1) * 16;
    size_t ld = (size_t)(j >> 1) * 2048;
    ua[j] = *(const uint4*)(OpA + od);
    ub[j] = *(const uint4*)(OpA + od + 2097152);
    la[j] = LpA[ld];
    lb[j] = LpA[ld + 65536];
    rB[j] = *(const bf16x8*)(Bsrc + j * 32);
  }
  *(bf16x8*)(abuf[0] + wo) = comb8(ua[0], ub[0], 1.0f / (la[0] + lb[0]));
  *(bf16x8*)(bbuf[0] + wo) = rB[0];
  __syncthreads();

  floatx16 acc = ZERO16;
  int mw = (wave & 1) * 32, nw = (wave >> 1) * 32;
  for (int it = 0; it < 16; ++it) {
    if (it < 14) {
      int jt = it + 2;
      size_t od = (size_t)(jt >> 1) * 65536 + (jt & 1) * 16;
      size_t ld = (size_t)(jt >> 1) * 2048;
      ua[it & 1] = *(const uint4*)(OpA + od);
      ub[it & 1] = *(const uint4*)(OpA + od + 2097152);
      la[it & 1] = LpA[ld];
      lb[it & 1] = LpA[ld + 65536];
      rB[it & 1] = *(const bf16x8*)(Bsrc + jt * 32);
    }
    const u16* ab = abuf[it & 1];
    const u16* bbf_ = bbuf[it & 1];
#pragma unroll
    for (int ks = 0; ks < 2; ++ks) {
      bf16x8 af = *(const bf16x8*)(ab + (mw + l31) * 40 + (2 * ks + half) * 8);
      bf16x8 bf = *(const bf16x8*)(bbf_ + (nw + l31) * 40 + (2 * ks + half) * 8);
      acc = MFMA32(af, bf, acc, 0, 0, 0);
    }
    if (it < 15) {
      int jn = (it + 1) & 1;
      *(bf16x8*)(abuf[jn] + wo) = comb8(ua[jn], ub[jn], 1.0f / (la[jn] + lb[jn]));
      *(bf16x8*)(bbuf[jn] + wo) = rB[jn];
    }
    __syncthreads();
  }

  int n = n0 + nw + l31;
  float bl = bo[n];
#pragma unroll
  for (int r = 0; r < 16; ++r) {
    int mm = m0 + mw + (r & 3) + 8 * (r >> 2) + 4 * half;
    out[(size_t)mm * DMODEL + n] = acc[r] + bl;
  }
}

// ---- flash attention, KEY-SPLIT x2 (unchanged from R2, control) ----
__global__ __launch_bounds__(256, 4) void attn_kernel(const u16* __restrict__ Q,
                                                      const u16* __restrict__ K,
                                                      const u16* __restrict__ Vt,
                                                      u32* __restrict__ Op,
                                                      float* __restrict__ Lp) {
  __shared__ __align__(16) u16 kbuf[2][64 * 72];
  __shared__ __align__(16) u16 vbuf[2][64 * 72];
  int tid = threadIdx.x;
  int lane = tid & 63, wave = tid >> 6;
  int l31 = lane & 31, half = lane >> 5;
  int bh = blockIdx.y;
  int b = bh >> 3, h = bh & 7, kv = h >> 2;
  int p = blockIdx.z;  // key half
  int q0 = blockIdx.x * 128 + wave * 32;
  const u16* Qh = Q + (size_t)(b * NH + h) * SDIM * HD;
  const u16* Kh = K + (size_t)(b * NKV + kv) * SDIM * HD + (size_t)p * 16 * 4096;
  const u16* Vh = Vt + (size_t)(b * NKV + kv) * HD * SDIM + p * 16 * 64;

  // Q B-frags: n = l31 (q row), k = ks*16 + half*8
  bf16x8 qf[4];
#pragma unroll
  for (int ks = 0; ks < 4; ++ks)
    qf[ks] = *(const bf16x8*)(Qh + (size_t)(q0 + l31) * HD + ks * 16 + half * 8);

  int ch = tid & 7, rr = tid >> 3;   // rr 0..31
  const u16* Ks0 = Kh + (size_t)(2 * rr) * HD + ch * 8;
  const u16* Ks1 = Kh + (size_t)(2 * rr + 1) * HD + ch * 8;
  const u16* Vs0 = Vh + (size_t)(2 * rr) * SDIM + ch * 8;
  const u16* Vs1 = Vh + (size_t)(2 * rr + 1) * SDIM + ch * 8;
  int w0 = rr * 72 + ch * 8, w1 = (rr + 32) * 72 + ch * 8;

  // stage tile 0 into buffer 0
  {
    bf16x8 k0 = *(const bf16x8*)Ks0;
    bf16x8 k1 = *(const bf16x8*)Ks1;
    bf16x8 v0 = *(const bf16x8*)Vs0;
    bf16x8 v1 = *(const bf16x8*)Vs1;
    *(bf16x8*)(kbuf[0] + w0) = k0; *(bf16x8*)(kbuf[0] + w1) = k1;
    *(bf16x8*)(vbuf[0] + w0) = v0; *(bf16x8*)(vbuf[0] + w1) = v1;
  }
  __syncthreads();

  floatx16 o0 = ZERO16, o1 = ZERO16;
  float sml = 0.0f;

  for (int it = 0; it < 16; ++it) {
    bf16x8 sK0, sK1, sV0, sV1;
    if (it < 15) {
      sK0 = *(const bf16x8*)(Ks0 + (size_t)(it + 1) * 4096);
      sK1 = *(const bf16x8*)(Ks1 + (size_t)(it + 1) * 4096);
      sV0 = *(const bf16x8*)(Vs0 + (it + 1) * 64);
      sV1 = *(const bf16x8*)(Vs1 + (it + 1) * 64);
    }
    const u16* kb = kbuf[it & 1];
    const u16* vb = vbuf[it & 1];

    // S^T = K . Q^T : col = q (lane), row = key (regs)
    floatx16 sa = ZERO16, sb = ZERO16;
#pragma unroll
    for (int ks = 0; ks < 4; ++ks) {
      int co = (2 * ks + half) * 8;
      bf16x8 kf0 = *(const bf16x8*)(kb + l31 * 72 + co);          // even keys
      bf16x8 kf1 = *(const bf16x8*)(kb + (32 + l31) * 72 + co);   // odd keys
      sa = MFMA32(kf0, qf[ks], sa, 0, 0, 0);
      sb = MFMA32(kf1, qf[ks], sb, 0, 0, 0);
    }

    // raw v_exp (log2 domain); pack (even,odd) P pairs in-register
    u32 pk[16];
#pragma unroll
    for (int r = 0; r < 16; ++r) {
      float p0 = __builtin_amdgcn_exp2f(sa[r]);
      float p1 = __builtin_amdgcn_exp2f(sb[r]);
      sml += p0 + p1;
      pk[r] = pkbf(p0, p1);
    }

    // PV: A-frag for k-step kc = pk[4kc+0..3] (lane-local, natural key order)
#pragma unroll
    for (int kc = 0; kc < 4; ++kc) {
      int co = (2 * kc + half) * 8;
      union { u32 u[4]; bf16x8 v; } pf;
      pf.u[0] = pk[4 * kc + 0]; pf.u[1] = pk[4 * kc + 1];
      pf.u[2] = pk[4 * kc + 2]; pf.u[3] = pk[4 * kc + 3];
      bf16x8 vf0 = *(const bf16x8*)(vb + l31 * 72 + co);          // even d
      bf16x8 vf1 = *(const bf16x8*)(vb + (32 + l31) * 72 + co);   // odd d
      o0 = MFMA32(pf.v, vf0, o0, 0, 0, 0);
      o1 = MFMA32(pf.v, vf1, o1, 0, 0, 0);
    }

    if (it < 15) {
      u16* kn = kbuf[(it + 1) & 1];
      u16* vn = vbuf[(it + 1) & 1];
      *(bf16x8*)(kn + w0) = sK0; *(bf16x8*)(kn + w1) = sK1;
      *(bf16x8*)(vn + w0) = sV0; *(bf16x8*)(vn + w1) = sV1;
      __syncthreads();  // next buffer visible; prev-parity reads all done
    }
  }

  // partial row sum for q = l31: combine the two key-half-lanes
  sml += __shfl_xor(sml, 32);

  size_t rowbase = ((size_t)(p * 32 + bh)) * SDIM;
#pragma unroll
  for (int r = 0; r < 16; ++r) {
    int q = (r & 3) + 8 * (r >> 2) + 4 * half;
    int s = q0 + q;
    Op[(rowbase + s) * 32 + l31] = pkbf(o0[r], o1[r]);  // unnormalized partial
  }
  if (lane < 32) Lp[rowbase + q0 + lane] = sml;
}

extern "C" void kernel_launch(void* const* d_in, const int* in_sizes, int n_in,
                              void* d_out, int out_size, void* d_ws, size_t ws_size,
                              hipStream_t stream) {
  const float* x  = (const float*)d_in[0];
  const float* Wq = (const float*)d_in[1];
  const float* bq = (const float*)d_in[2];
  const float* Wk = (const float*)d_in[3];
  const float* bk = (const float*)d_in[4];
  const float* Wv = (const float*)d_in[5];
  const float* bv = (const float*)d_in[6];
  const float* Wo = (const float*)d_in[7];
  const float* bo = (const float*)d_in[8];
  float* out = (float*)d_out;

  const size_t M = (size_t)BATCH * SDIM;  // 8192
  u16* WT  = (u16*)d_ws;                  // 1280*512
  u16* Qb  = WT  + 1280 * DMODEL;         // 8192*512  [B,NH,S,64]
  u16* Kb  = Qb  + M * DMODEL;            // 8192*128  [B,NKV,S,64]
  u16* VtB = Kb  + M * 128;               // 8192*128  [B,NKV,64,S]
  u32* Op  = (u32*)(VtB + M * 128);       // 2*32*2048*32 u32 (16.8 MB partials)
  float* Lp = (float*)(Op + (size_t)2 * 32 * SDIM * 32);  // 2*32*2048 f32

  cvt_kernel<<<2560, 256, 0, stream>>>(Wq, Wk, Wv, Wo, WT);
  gemm_qkv_kernel<<<dim3(768 / 64, M / 64), 256, 0, stream>>>(x, WT, bq, bk, bv, Qb, Kb, VtB);
  attn_kernel<<<dim3(SDIM / 128, BATCH * NH, 2), 256, 0, stream>>>(Qb, Kb, VtB, Op, Lp);
  gemm_out_kernel<<<dim3(512 / 64, M / 64), 256, 0, stream>>>(Op, Lp, WT + (size_t)768 * DMODEL, bo, out);
}

// Round 5
// 157.440 us; speedup vs baseline: 1.0805x; 1.0805x over previous
//
#include <hip/hip_runtime.h>
#include <hip/hip_bf16.h>

#define SDIM 2048
#define BATCH 4
#define DMODEL 512
#define NH 8
#define NKV 2
#define HD 64

typedef __bf16 bf16x8 __attribute__((ext_vector_type(8)));
typedef float floatx16 __attribute__((ext_vector_type(16)));
typedef unsigned short u16;
typedef unsigned int u32;

#define MFMA32 __builtin_amdgcn_mfma_f32_32x32x16_bf16
#define ZERO16 {0.f,0.f,0.f,0.f,0.f,0.f,0.f,0.f,0.f,0.f,0.f,0.f,0.f,0.f,0.f,0.f}
// softmax scale with log2(e) folded: exp(s*0.125) = exp2(s*0.125*log2e)
#define QSCALE 0.18033688011112042f

__device__ __forceinline__ u16 f2bf(float f) {
  union { float f; u32 u; } a; a.f = f;
  u32 r = a.u + 0x7fffu + ((a.u >> 16) & 1u);
  return (u16)(r >> 16);
}
// pack two f32 -> (lo, hi) bf16 pair via v_cvt_pk_bf16_f32
__device__ __forceinline__ u32 pkbf(float lo, float hi) {
  __hip_bfloat162 h = __float22bfloat162_rn(float2{lo, hi});
  union { __hip_bfloat162 h; u32 u; } c; c.h = h;
  return c.u;
}

// ---- fused conversions: x fp32->bf16 (blocks 0..4095), weights -> WT[1280][512]
// bf16 transposed (blocks 4096..6655) ----
__global__ __launch_bounds__(256) void cvt_kernel(const float* __restrict__ x,
                                                  const float* __restrict__ Wq,
                                                  const float* __restrict__ Wk,
                                                  const float* __restrict__ Wv,
                                                  const float* __restrict__ Wo,
                                                  u16* __restrict__ xb,
                                                  u16* __restrict__ WT) {
  int bid = blockIdx.x;
  if (bid < 4096) {
    int i = bid * 256 + threadIdx.x;
    float4 v = reinterpret_cast<const float4*>(x)[i];
    uint2 o = {pkbf(v.x, v.y), pkbf(v.z, v.w)};
    reinterpret_cast<uint2*>(xb)[i] = o;
  } else {
    int i = (bid - 4096) * 256 + threadIdx.x;  // < 1280*512
    int n = i >> 9, k = i & 511;
    float v;
    if (n < 512)       v = Wq[k * 512 + n];
    else if (n < 640)  v = Wk[k * 128 + (n - 512)];
    else if (n < 768)  v = Wv[k * 128 + (n - 640)];
    else               v = Wo[k * 512 + (n - 768)];
    WT[i] = f2bf(v);
  }
}

// ---- fused QKV projection: 128x128 tile, BK=32, distance-2 register prefetch,
// LDS dbuf stride-40 (40 KB), 32x32 MFMA, 4 waves (2m x 2n), each wave owns a
// 64x64 sub-tile (2x2 acc). 8 MFMA : 8 ds_read_b128 per wave-iter (4x the
// matrix work per barrier vs the 64x64 version). Q scaled by QSCALE;
// Q/K head-major [B,nh,S,64]; V written TRANSPOSED [B,NKV,64,S].
__global__ __launch_bounds__(256, 2) void gemm_qkv_kernel(const u16* __restrict__ A,
                                                          const u16* __restrict__ WT,
                                                          const float* __restrict__ bq,
                                                          const float* __restrict__ bk,
                                                          const float* __restrict__ bv,
                                                          u16* __restrict__ Qb,
                                                          u16* __restrict__ Kb,
                                                          u16* __restrict__ Vt) {
  __shared__ __align__(16) u16 abuf[2][128 * 40];
  __shared__ __align__(16) u16 bbuf[2][128 * 40];
  int tid = threadIdx.x;
  int lane = tid & 63, wave = tid >> 6;
  int l31 = lane & 31, half = lane >> 5;
  int m0 = blockIdx.y * 128;
  int n0 = blockIdx.x * 128;
  int row = tid >> 2, ch = tid & 3;   // row 0..63, 4 chunks of 8 cover BK=32
  const u16* Asrc = A + (size_t)(m0 + row) * DMODEL + ch * 8;
  const u16* Bsrc = WT + (size_t)(n0 + row) * DMODEL + ch * 8;
  int wo = row * 40 + ch * 8;

  bf16x8 rA[2][2], rB[2][2];   // [slot][row-group g: rows r / r+64]
#pragma unroll
  for (int g = 0; g < 2; ++g) {
    rA[0][g] = *(const bf16x8*)(Asrc + (size_t)g * 64 * DMODEL);
    rB[0][g] = *(const bf16x8*)(Bsrc + (size_t)g * 64 * DMODEL);
    rA[1][g] = *(const bf16x8*)(Asrc + (size_t)g * 64 * DMODEL + 32);
    rB[1][g] = *(const bf16x8*)(Bsrc + (size_t)g * 64 * DMODEL + 32);
  }
#pragma unroll
  for (int g = 0; g < 2; ++g) {
    *(bf16x8*)(abuf[0] + wo + g * 64 * 40) = rA[0][g];
    *(bf16x8*)(bbuf[0] + wo + g * 64 * 40) = rB[0][g];
  }
  __syncthreads();

  floatx16 acc[2][2] = {{ZERO16, ZERO16}, {ZERO16, ZERO16}};
  int mw = (wave & 1) * 64, nw = (wave >> 1) * 64;
#pragma unroll 2
  for (int it = 0; it < 16; ++it) {
    if (it < 14) {
#pragma unroll
      for (int g = 0; g < 2; ++g) {
        rA[it & 1][g] = *(const bf16x8*)(Asrc + (size_t)g * 64 * DMODEL + (it + 2) * 32);
        rB[it & 1][g] = *(const bf16x8*)(Bsrc + (size_t)g * 64 * DMODEL + (it + 2) * 32);
      }
    }
    const u16* ab = abuf[it & 1];
    const u16* bbp = bbuf[it & 1];
#pragma unroll
    for (int ks = 0; ks < 2; ++ks) {
      int co = (2 * ks + half) * 8;
      bf16x8 a0 = *(const bf16x8*)(ab + (mw + l31) * 40 + co);
      bf16x8 a1 = *(const bf16x8*)(ab + (mw + 32 + l31) * 40 + co);
      bf16x8 b0 = *(const bf16x8*)(bbp + (nw + l31) * 40 + co);
      bf16x8 b1 = *(const bf16x8*)(bbp + (nw + 32 + l31) * 40 + co);
      acc[0][0] = MFMA32(a0, b0, acc[0][0], 0, 0, 0);
      acc[0][1] = MFMA32(a0, b1, acc[0][1], 0, 0, 0);
      acc[1][0] = MFMA32(a1, b0, acc[1][0], 0, 0, 0);
      acc[1][1] = MFMA32(a1, b1, acc[1][1], 0, 0, 0);
    }
    if (it < 15) {
#pragma unroll
      for (int g = 0; g < 2; ++g) {
        *(bf16x8*)(abuf[(it + 1) & 1] + wo + g * 64 * 40) = rA[(it + 1) & 1][g];
        *(bf16x8*)(bbuf[(it + 1) & 1] + wo + g * 64 * 40) = rB[(it + 1) & 1][g];
      }
    }
    __syncthreads();
  }

  int b4 = m0 >> 11;  // batch fixed per block (m-tile within one batch)
#pragma unroll
  for (int ns = 0; ns < 2; ++ns) {
    int col = n0 + nw + ns * 32 + l31;
    if (col >= 640) {
      // V: write transposed rows of Vt[b,kv,d,s] as ushort4 (4 consecutive s)
      int lc = col - 640;
      float bl = bv[lc];
      int hkv = lc >> 6, d = lc & 63;
      u16* vrow = Vt + ((size_t)(b4 * NKV + hkv) * HD + d) * SDIM;
#pragma unroll
      for (int ms = 0; ms < 2; ++ms) {
#pragma unroll
        for (int g = 0; g < 4; ++g) {
          int s = (m0 + mw + ms * 32 + 8 * g + 4 * half) & 2047;
          ushort4 t;
          t.x = f2bf(acc[ms][ns][4 * g + 0] + bl);
          t.y = f2bf(acc[ms][ns][4 * g + 1] + bl);
          t.z = f2bf(acc[ms][ns][4 * g + 2] + bl);
          t.w = f2bf(acc[ms][ns][4 * g + 3] + bl);
          *(ushort4*)(vrow + s) = t;
        }
      }
    } else {
      u16* outp; const float* bias; float scale; int nhreg, lc;
      if (col < 512) { outp = Qb; bias = bq; scale = QSCALE; nhreg = NH;  lc = col; }
      else           { outp = Kb; bias = bk; scale = 1.0f;   nhreg = NKV; lc = col - 512; }
      float bl = bias[lc];
      int h = lc >> 6, d = lc & 63;
      u16* base = outp + ((size_t)(b4 * nhreg + h) * SDIM) * HD + d;
#pragma unroll
      for (int ms = 0; ms < 2; ++ms) {
#pragma unroll
        for (int r = 0; r < 16; ++r) {
          int s = (m0 + mw + ms * 32 + (r & 3) + 8 * (r >> 2) + 4 * half) & 2047;
          base[(size_t)s * HD] = f2bf((acc[ms][ns][r] + bl) * scale);
        }
      }
    }
  }
}

// ---- O projection: 128x128 tile, same pipeline, fp32 output ----
__global__ __launch_bounds__(256, 2) void gemm_out_kernel(const u16* __restrict__ A,
                                                          const u16* __restrict__ WTo,
                                                          const float* __restrict__ bo,
                                                          float* __restrict__ out) {
  __shared__ __align__(16) u16 abuf[2][128 * 40];
  __shared__ __align__(16) u16 bbuf[2][128 * 40];
  int tid = threadIdx.x;
  int lane = tid & 63, wave = tid >> 6;
  int l31 = lane & 31, half = lane >> 5;
  int m0 = blockIdx.y * 128;
  int n0 = blockIdx.x * 128;
  int row = tid >> 2, ch = tid & 3;
  const u16* Asrc = A + (size_t)(m0 + row) * DMODEL + ch * 8;
  const u16* Bsrc = WTo + (size_t)(n0 + row) * DMODEL + ch * 8;
  int wo = row * 40 + ch * 8;

  bf16x8 rA[2][2], rB[2][2];
#pragma unroll
  for (int g = 0; g < 2; ++g) {
    rA[0][g] = *(const bf16x8*)(Asrc + (size_t)g * 64 * DMODEL);
    rB[0][g] = *(const bf16x8*)(Bsrc + (size_t)g * 64 * DMODEL);
    rA[1][g] = *(const bf16x8*)(Asrc + (size_t)g * 64 * DMODEL + 32);
    rB[1][g] = *(const bf16x8*)(Bsrc + (size_t)g * 64 * DMODEL + 32);
  }
#pragma unroll
  for (int g = 0; g < 2; ++g) {
    *(bf16x8*)(abuf[0] + wo + g * 64 * 40) = rA[0][g];
    *(bf16x8*)(bbuf[0] + wo + g * 64 * 40) = rB[0][g];
  }
  __syncthreads();

  floatx16 acc[2][2] = {{ZERO16, ZERO16}, {ZERO16, ZERO16}};
  int mw = (wave & 1) * 64, nw = (wave >> 1) * 64;
#pragma unroll 2
  for (int it = 0; it < 16; ++it) {
    if (it < 14) {
#pragma unroll
      for (int g = 0; g < 2; ++g) {
        rA[it & 1][g] = *(const bf16x8*)(Asrc + (size_t)g * 64 * DMODEL + (it + 2) * 32);
        rB[it & 1][g] = *(const bf16x8*)(Bsrc + (size_t)g * 64 * DMODEL + (it + 2) * 32);
      }
    }
    const u16* ab = abuf[it & 1];
    const u16* bbp = bbuf[it & 1];
#pragma unroll
    for (int ks = 0; ks < 2; ++ks) {
      int co = (2 * ks + half) * 8;
      bf16x8 a0 = *(const bf16x8*)(ab + (mw + l31) * 40 + co);
      bf16x8 a1 = *(const bf16x8*)(ab + (mw + 32 + l31) * 40 + co);
      bf16x8 b0 = *(const bf16x8*)(bbp + (nw + l31) * 40 + co);
      bf16x8 b1 = *(const bf16x8*)(bbp + (nw + 32 + l31) * 40 + co);
      acc[0][0] = MFMA32(a0, b0, acc[0][0], 0, 0, 0);
      acc[0][1] = MFMA32(a0, b1, acc[0][1], 0, 0, 0);
      acc[1][0] = MFMA32(a1, b0, acc[1][0], 0, 0, 0);
      acc[1][1] = MFMA32(a1, b1, acc[1][1], 0, 0, 0);
    }
    if (it < 15) {
#pragma unroll
      for (int g = 0; g < 2; ++g) {
        *(bf16x8*)(abuf[(it + 1) & 1] + wo + g * 64 * 40) = rA[(it + 1) & 1][g];
        *(bf16x8*)(bbuf[(it + 1) & 1] + wo + g * 64 * 40) = rB[(it + 1) & 1][g];
      }
    }
    __syncthreads();
  }

#pragma unroll
  for (int ns = 0; ns < 2; ++ns) {
    int n = n0 + nw + ns * 32 + l31;
    float bl = bo[n];
#pragma unroll
    for (int ms = 0; ms < 2; ++ms) {
#pragma unroll
      for (int r = 0; r < 16; ++r) {
        int m = m0 + mw + ms * 32 + (r & 3) + 8 * (r >> 2) + 4 * half;
        out[(size_t)m * DMODEL + n] = acc[ms][ns][r] + bl;
      }
    }
  }
}

// ---- flash attention: 32x32x16 MFMA, 4 waves x 32 q-rows (128/block), 64 keys/iter.
// SWAPPED QK^T (mfma(K,Q)) -> S^T with q on lanes, keys in regs. With the
// even/odd key interleave, the PV A-fragment for k-step kc is exactly
// pkbf(exp2(sa[4kc+u]), exp2(sb[4kc+u])) lane-locally -> P never touches LDS.
// K/V double-buffered in LDS (36 KB), ONE barrier/iter, register prefetch.
__global__ __launch_bounds__(256, 2) void attn_kernel(const u16* __restrict__ Q,
                                                      const u16* __restrict__ K,
                                                      const u16* __restrict__ Vt,
                                                      u16* __restrict__ O) {
  __shared__ __align__(16) u16 kbuf[2][64 * 72];
  __shared__ __align__(16) u16 vbuf[2][64 * 72];
  int tid = threadIdx.x;
  int lane = tid & 63, wave = tid >> 6;
  int l31 = lane & 31, half = lane >> 5;
  int bh = blockIdx.y;
  int b = bh >> 3, h = bh & 7, kv = h >> 2;
  int q0 = blockIdx.x * 128 + wave * 32;
  const u16* Qh = Q + (size_t)(b * NH + h) * SDIM * HD;
  const u16* Kh = K + (size_t)(b * NKV + kv) * SDIM * HD;
  const u16* Vh = Vt + (size_t)(b * NKV + kv) * HD * SDIM;

  // Q B-frags: n = l31 (q row), k = ks*16 + half*8
  bf16x8 qf[4];
#pragma unroll
  for (int ks = 0; ks < 4; ++ks)
    qf[ks] = *(const bf16x8*)(Qh + (size_t)(q0 + l31) * HD + ks * 16 + half * 8);

  int ch = tid & 7, rr = tid >> 3;   // rr 0..31
  const u16* Ks0 = Kh + (size_t)(2 * rr) * HD + ch * 8;
  const u16* Ks1 = Kh + (size_t)(2 * rr + 1) * HD + ch * 8;
  const u16* Vs0 = Vh + (size_t)(2 * rr) * SDIM + ch * 8;
  const u16* Vs1 = Vh + (size_t)(2 * rr + 1) * SDIM + ch * 8;
  int w0 = rr * 72 + ch * 8, w1 = (rr + 32) * 72 + ch * 8;

  // stage tile 0 into buffer 0
  {
    bf16x8 k0 = *(const bf16x8*)Ks0;
    bf16x8 k1 = *(const bf16x8*)Ks1;
    bf16x8 v0 = *(const bf16x8*)Vs0;
    bf16x8 v1 = *(const bf16x8*)Vs1;
    *(bf16x8*)(kbuf[0] + w0) = k0; *(bf16x8*)(kbuf[0] + w1) = k1;
    *(bf16x8*)(vbuf[0] + w0) = v0; *(bf16x8*)(vbuf[0] + w1) = v1;
  }
  __syncthreads();

  floatx16 o0 = ZERO16, o1 = ZERO16;
  float sml = 0.0f;

  for (int it = 0; it < 32; ++it) {
    bf16x8 sK0, sK1, sV0, sV1;
    if (it < 31) {
      sK0 = *(const bf16x8*)(Ks0 + (size_t)(it + 1) * 4096);
      sK1 = *(const bf16x8*)(Ks1 + (size_t)(it + 1) * 4096);
      sV0 = *(const bf16x8*)(Vs0 + (it + 1) * 64);
      sV1 = *(const bf16x8*)(Vs1 + (it + 1) * 64);
    }
    const u16* kb = kbuf[it & 1];
    const u16* vb = vbuf[it & 1];

    // S^T = K . Q^T : col = q (lane), row = key (regs)
    floatx16 sa = ZERO16, sb = ZERO16;
#pragma unroll
    for (int ks = 0; ks < 4; ++ks) {
      int co = (2 * ks + half) * 8;
      bf16x8 kf0 = *(const bf16x8*)(kb + l31 * 72 + co);          // even keys
      bf16x8 kf1 = *(const bf16x8*)(kb + (32 + l31) * 72 + co);   // odd keys
      sa = MFMA32(kf0, qf[ks], sa, 0, 0, 0);
      sb = MFMA32(kf1, qf[ks], sb, 0, 0, 0);
    }

    // raw v_exp (log2 domain); pack (even,odd) P pairs in-register
    u32 pk[16];
#pragma unroll
    for (int r = 0; r < 16; ++r) {
      float p0 = __builtin_amdgcn_exp2f(sa[r]);
      float p1 = __builtin_amdgcn_exp2f(sb[r]);
      sml += p0 + p1;
      pk[r] = pkbf(p0, p1);
    }

    // PV: A-frag for k-step kc = pk[4kc+0..3] (lane-local, natural key order)
#pragma unroll
    for (int kc = 0; kc < 4; ++kc) {
      int co = (2 * kc + half) * 8;
      union { u32 u[4]; bf16x8 v; } pf;
      pf.u[0] = pk[4 * kc + 0]; pf.u[1] = pk[4 * kc + 1];
      pf.u[2] = pk[4 * kc + 2]; pf.u[3] = pk[4 * kc + 3];
      bf16x8 vf0 = *(const bf16x8*)(vb + l31 * 72 + co);          // even d
      bf16x8 vf1 = *(const bf16x8*)(vb + (32 + l31) * 72 + co);   // odd d
      o0 = MFMA32(pf.v, vf0, o0, 0, 0, 0);
      o1 = MFMA32(pf.v, vf1, o1, 0, 0, 0);
    }

    if (it < 31) {
      u16* kn = kbuf[(it + 1) & 1];
      u16* vn = vbuf[(it + 1) & 1];
      *(bf16x8*)(kn + w0) = sK0; *(bf16x8*)(kn + w1) = sK1;
      *(bf16x8*)(vn + w0) = sV0; *(bf16x8*)(vn + w1) = sV1;
      __syncthreads();  // next buffer visible; prev-parity reads all done
    }
  }

  // total row sum for q = l31: combine the two key-half-lanes
  sml += __shfl_xor(sml, 32);

#pragma unroll
  for (int r = 0; r < 16; ++r) {
    int q = (r & 3) + 8 * (r >> 2) + 4 * half;
    float inv = 1.0f / __shfl(sml, q);
    int s = q0 + q;
    u32* dst = (u32*)(O + ((size_t)(b * SDIM + s) * DMODEL + h * HD));
    dst[l31] = pkbf(o0[r] * inv, o1[r] * inv);
  }
}

extern "C" void kernel_launch(void* const* d_in, const int* in_sizes, int n_in,
                              void* d_out, int out_size, void* d_ws, size_t ws_size,
                              hipStream_t stream) {
  const float* x  = (const float*)d_in[0];
  const float* Wq = (const float*)d_in[1];
  const float* bq = (const float*)d_in[2];
  const float* Wk = (const float*)d_in[3];
  const float* bk = (const float*)d_in[4];
  const float* Wv = (const float*)d_in[5];
  const float* bv = (const float*)d_in[6];
  const float* Wo = (const float*)d_in[7];
  const float* bo = (const float*)d_in[8];
  float* out = (float*)d_out;

  const size_t M = (size_t)BATCH * SDIM;  // 8192
  u16* xb  = (u16*)d_ws;                  // 8192*512
  u16* WT  = xb  + M * DMODEL;            // 1280*512
  u16* Qb  = WT  + 1280 * DMODEL;         // 8192*512  [B,NH,S,64]
  u16* Kb  = Qb  + M * DMODEL;            // 8192*128  [B,NKV,S,64]
  u16* VtB = Kb  + M * 128;               // 8192*128  [B,NKV,64,S]
  u16* Ab  = VtB + M * 128;               // 8192*512  [B,S,512]

  cvt_kernel<<<4096 + 2560, 256, 0, stream>>>(x, Wq, Wk, Wv, Wo, xb, WT);
  gemm_qkv_kernel<<<dim3(768 / 128, M / 128), 256, 0, stream>>>(xb, WT, bq, bk, bv, Qb, Kb, VtB);
  attn_kernel<<<dim3(SDIM / 128, BATCH * NH), 256, 0, stream>>>(Qb, Kb, VtB, Ab);
  gemm_out_kernel<<<dim3(512 / 128, M / 128), 256, 0, stream>>>(Ab, WT + (size_t)768 * DMODEL, bo, out);
}